// Round 2
// baseline (145.814 us; speedup 1.0000x reference)
//
#include <hip/hip_runtime.h>
#include <math.h>

#define NE 16   // electrons
#define NA 4    // atoms
#define NB 4    // basis
#define NK 8    // kernel
#define NM 16   // embed
#define NL 2    // layers

typedef float f32x2 __attribute__((ext_vector_type(2)));

__device__ __forceinline__ float ssp(float x) {
    // softplus(x) - ln2 == max(x,0) + ln2*log2(1 + 2^(-|x|*log2e)) - ln2
    float t  = __builtin_amdgcn_exp2f(-1.44269504088896f * fabsf(x)); // e^{-|x|}, in (0,1]
    float lg = __builtin_amdgcn_logf(1.0f + t);                       // log2(1+t)
    return fmaf(0.69314718055995f, lg, fmaxf(x, 0.0f) - 0.69314718055995f);
}

__global__ void __launch_bounds__(256) jastrow_kernel(
    const float* __restrict__ edges_elec,  // [B,16,16,4]
    const float* __restrict__ edges_nuc,   // [B,16,4,4]
    const float* __restrict__ x_init,      // [16,16]
    const float* __restrict__ Y,           // [4,8]
    const float* __restrict__ wW1,         // [2,3,4,8]
    const float* __restrict__ wb1,         // [2,3,8]
    const float* __restrict__ wW2,         // [2,3,8,8]
    const float* __restrict__ wb2,         // [2,3,8]
    const float* __restrict__ hW,          // [2,16,8]
    const float* __restrict__ hb,          // [2,8]
    const float* __restrict__ gW1,         // [2,3,8,8]
    const float* __restrict__ gb1,         // [2,3,8]
    const float* __restrict__ gW2,         // [2,3,8,16]
    const float* __restrict__ gb2,         // [2,3,16]
    const float* __restrict__ oW,          // [16]
    const float* __restrict__ ob,          // [1]
    float* __restrict__ out, int B)
{
    __shared__ f32x2 hx2_lds[4][NE][4];    // per-wave hx broadcast (2 KB)

    const int tid  = threadIdx.x;
    const int wv   = tid >> 6;             // wave in block (0..3)
    const int lane = tid & 63;
    const int i    = lane >> 2;            // electron row 0..15
    const int q    = lane & 3;             // quarter-lane 0..3

    int b = blockIdx.x * 4 + wv;
    if (b >= B) b = B - 1;                 // harmless duplicate work; keeps barriers uniform
    const bool alive = (blockIdx.x * 4 + wv < B);

    const int sbase = (i < 8) ? 0 : 8;     // same-spin j block
    const int abase = (i < 8) ? 8 : 0;     // anti-spin j block

    // ---- load all edge features for this lane's pairs once (reused across layers) ----
    const float4* Ee = reinterpret_cast<const float4*>(edges_elec) + (size_t)b * (NE * NE);
    const float4 Es0 = Ee[i * NE + sbase + q];
    const float4 Es1 = Ee[i * NE + sbase + q + 4];
    const float4 Ea0 = Ee[i * NE + abase + q];
    const float4 Ea1 = Ee[i * NE + abase + q + 4];
    const float4* En = reinterpret_cast<const float4*>(edges_nuc) + (size_t)b * (NE * NA);
    const float4 Enu = En[i * NA + q];

    // ---- x: lane owns x[i][q*4 .. q*4+3] as 2x f32x2 ----
    f32x2 xe[2];
    {
        const f32x2* Xi = reinterpret_cast<const f32x2*>(x_init + i * NM + q * 4);
        xe[0] = Xi[0]; xe[1] = Xi[1];
    }

    // filter subnet: t2 = ssp(e @ W1 + b1) @ W2 + b2 (k processed as f32x2 pairs)
    auto filt = [&](const float4& e, int lc, f32x2 (&t2)[4]) {
        const f32x2* W1 = reinterpret_cast<const f32x2*>(wW1 + lc * NB * NK);
        const f32x2* B1 = reinterpret_cast<const f32x2*>(wb1 + lc * NK);
        const f32x2* W2 = reinterpret_cast<const f32x2*>(wW2 + lc * NK * NK);
        const f32x2* B2 = reinterpret_cast<const f32x2*>(wb2 + lc * NK);
        float s[NK];
        #pragma unroll
        for (int k2 = 0; k2 < 4; ++k2) {
            f32x2 a = B1[k2];
            a += e.x * W1[0 * 4 + k2];
            a += e.y * W1[1 * 4 + k2];
            a += e.z * W1[2 * 4 + k2];
            a += e.w * W1[3 * 4 + k2];
            s[2 * k2]     = ssp(a.x);
            s[2 * k2 + 1] = ssp(a.y);
        }
        #pragma unroll
        for (int k2 = 0; k2 < 4; ++k2) {
            f32x2 a = B2[k2];
            #pragma unroll
            for (int kk = 0; kk < NK; ++kk)
                a += s[kk] * W2[kk * 4 + k2];
            t2[k2] = a;
        }
    };

    #pragma unroll
    for (int l = 0; l < NL; ++l) {
        // ---- hx = x @ hW + hb : partials over lane's 4 embed dims, butterfly over q ----
        f32x2 hx2[4];
        {
            const f32x2* Hw = reinterpret_cast<const f32x2*>(hW + l * NM * NK);
            #pragma unroll
            for (int k2 = 0; k2 < 4; ++k2) {
                f32x2 a = xe[0].x * Hw[(q * 4 + 0) * 4 + k2];
                a += xe[0].y * Hw[(q * 4 + 1) * 4 + k2];
                a += xe[1].x * Hw[(q * 4 + 2) * 4 + k2];
                a += xe[1].y * Hw[(q * 4 + 3) * 4 + k2];
                hx2[k2] = a;
            }
        }
        {
            const f32x2* Hb = reinterpret_cast<const f32x2*>(hb + l * NK);
            #pragma unroll
            for (int k2 = 0; k2 < 4; ++k2) {
                hx2[k2].x += __shfl_xor(hx2[k2].x, 1);
                hx2[k2].x += __shfl_xor(hx2[k2].x, 2);
                hx2[k2].y += __shfl_xor(hx2[k2].y, 1);
                hx2[k2].y += __shfl_xor(hx2[k2].y, 2);
                hx2[k2] += Hb[k2];         // bias AFTER the q-reduction
            }
        }
        __syncthreads();                   // WAR: prior layer's reads done before overwrite
        hx2_lds[wv][i][q] = hx2[q];        // 4 lanes of the q-group cover k=0..7
        __syncthreads();                   // writes visible before reads

        f32x2 z0[4] = {{0,0},{0,0},{0,0},{0,0}};  // same-spin channel
        f32x2 z1[4] = {{0,0},{0,0},{0,0},{0,0}};  // anti-spin channel
        f32x2 zn[4];                               // nuclear channel

        // ---- same-spin pairs (channel 0): j = sbase + q + 4t, diagonal masked ----
        #pragma unroll
        for (int t = 0; t < 2; ++t) {
            const int j = sbase + q + 4 * t;
            f32x2 t2[4];
            filt((t == 0) ? Es0 : Es1, l * 3 + 0, t2);
            const float msk = (j == i) ? 0.f : 1.f;
            #pragma unroll
            for (int k2 = 0; k2 < 4; ++k2)
                z0[k2] += (msk * t2[k2]) * hx2_lds[wv][j][k2];
        }
        // ---- anti-spin pairs (channel 1): j = abase + q + 4t ----
        #pragma unroll
        for (int t = 0; t < 2; ++t) {
            const int j = abase + q + 4 * t;
            f32x2 t2[4];
            filt((t == 0) ? Ea0 : Ea1, l * 3 + 1, t2);
            #pragma unroll
            for (int k2 = 0; k2 < 4; ++k2)
                z1[k2] += t2[k2] * hx2_lds[wv][j][k2];
        }
        // ---- nuclear channel (2): atom a = q ----
        {
            f32x2 t2[4];
            filt(Enu, l * 3 + 2, t2);
            const f32x2* Yv = reinterpret_cast<const f32x2*>(Y + q * NK);
            #pragma unroll
            for (int k2 = 0; k2 < 4; ++k2)
                zn[k2] = t2[k2] * Yv[k2];
        }

        // ---- reduce z over the 4-lane q-group (sums each channel over its j/a subsets) ----
        float zr0[NK], zr1[NK], zrn[NK];
        #pragma unroll
        for (int k2 = 0; k2 < 4; ++k2) {
            float a;
            a = z0[k2].x; a += __shfl_xor(a, 1); a += __shfl_xor(a, 2); zr0[2*k2]   = a;
            a = z0[k2].y; a += __shfl_xor(a, 1); a += __shfl_xor(a, 2); zr0[2*k2+1] = a;
            a = z1[k2].x; a += __shfl_xor(a, 1); a += __shfl_xor(a, 2); zr1[2*k2]   = a;
            a = z1[k2].y; a += __shfl_xor(a, 1); a += __shfl_xor(a, 2); zr1[2*k2+1] = a;
            a = zn[k2].x; a += __shfl_xor(a, 1); a += __shfl_xor(a, 2); zrn[2*k2]   = a;
            a = zn[k2].y; a += __shfl_xor(a, 1); a += __shfl_xor(a, 2); zrn[2*k2+1] = a;
        }

        // ---- g-nets: upd[i][e] for lane's 4 embed dims e = q*4+m ----
        f32x2 upd[2] = {{0,0},{0,0}};
        auto gnet = [&](const float (&z)[NK], int lc) {
            const f32x2* G1  = reinterpret_cast<const f32x2*>(gW1 + lc * NK * NK);
            const f32x2* Gb1 = reinterpret_cast<const f32x2*>(gb1 + lc * NK);
            float g[NK];
            #pragma unroll
            for (int k2 = 0; k2 < 4; ++k2) {
                f32x2 a = Gb1[k2];
                #pragma unroll
                for (int k = 0; k < NK; ++k)
                    a += z[k] * G1[k * 4 + k2];
                g[2 * k2]     = ssp(a.x);
                g[2 * k2 + 1] = ssp(a.y);
            }
            const f32x2* G2  = reinterpret_cast<const f32x2*>(gW2 + lc * NK * NM);
            const f32x2* Gb2 = reinterpret_cast<const f32x2*>(gb2 + lc * NM);
            #pragma unroll
            for (int m2 = 0; m2 < 2; ++m2) {
                f32x2 a = Gb2[q * 2 + m2];
                #pragma unroll
                for (int kk = 0; kk < NK; ++kk)
                    a += g[kk] * G2[kk * 8 + q * 2 + m2];
                upd[m2] += a;
            }
        };
        gnet(zr0, l * 3 + 0);
        gnet(zr1, l * 3 + 1);
        gnet(zrn, l * 3 + 2);

        xe[0] += upd[0];
        xe[1] += upd[1];
    }

    // ---- readout: sum_{i,e} x[i][e]*oW[e] + 16*ob ----
    const f32x2* O2 = reinterpret_cast<const f32x2*>(oW + q * 4);
    f32x2 p2 = xe[0] * O2[0] + xe[1] * O2[1];
    float part = p2.x + p2.y;
    #pragma unroll
    for (int off = 1; off < 64; off <<= 1) part += __shfl_xor(part, off);

    if (alive && lane == 0) out[b] = part + 16.f * ob[0];
}

extern "C" void kernel_launch(void* const* d_in, const int* in_sizes, int n_in,
                              void* d_out, int out_size, void* d_ws, size_t ws_size,
                              hipStream_t stream) {
    const float* edges_elec = (const float*)d_in[0];
    const float* edges_nuc  = (const float*)d_in[1];
    const float* x_init     = (const float*)d_in[2];
    const float* Yp         = (const float*)d_in[3];
    const float* wW1        = (const float*)d_in[4];
    const float* wb1        = (const float*)d_in[5];
    const float* wW2        = (const float*)d_in[6];
    const float* wb2        = (const float*)d_in[7];
    const float* hW         = (const float*)d_in[8];
    const float* hb         = (const float*)d_in[9];
    const float* gW1        = (const float*)d_in[10];
    const float* gb1        = (const float*)d_in[11];
    const float* gW2        = (const float*)d_in[12];
    const float* gb2        = (const float*)d_in[13];
    const float* oW         = (const float*)d_in[14];
    const float* ob         = (const float*)d_in[15];
    float* out = (float*)d_out;

    const int B = in_sizes[0] / (NE * NE * NB);   // 8192
    const int grid = (B + 3) / 4;                 // 4 batch elems (waves) per 256-thread block

    hipLaunchKernelGGL(jastrow_kernel, dim3(grid), dim3(256), 0, stream,
                       edges_elec, edges_nuc, x_init, Yp, wW1, wb1, wW2, wb2,
                       hW, hb, gW1, gb1, gW2, gb2, oW, ob, out, B);
}